// Round 1
// baseline (5734.857 us; speedup 1.0000x reference)
//
#include <hip/hip_runtime.h>
#include <math.h>

#define RDIM 128
#define CDIM 512
#define EDIM 768
#define HDIM 12
#define DDIM 64
#define MDIM (RDIM*CDIM)                 // 65536 tokens
#define OUT_ELEMS ((size_t)MDIM*EDIM)    // 50331648 floats (output part of d_out)

// ============================================================================
// GEMM with bias and scale: out[m][n] = (sum_k A[m][k]*W[k][n] + b[n]) * scale
// A: [M][768] row-major, W: [768][768] row-major, out: [M][768]
// 128x128 tile, BK=8, 256 threads, 8x8 microtile per thread.
// ============================================================================
__global__ __launch_bounds__(256)
void sgemm_bias(const float* __restrict__ A, const float* __restrict__ W,
                const float* __restrict__ bias, float* __restrict__ out,
                float scale) {
    __shared__ float As[8][132];   // [k][m], pad 132 (528B rows, 16B aligned)
    __shared__ float Bs[8][132];   // [k][n]
    const int bm = blockIdx.x * 128;
    const int bn = blockIdx.y * 128;
    const int tid = threadIdx.x;
    const int tx = tid & 15, ty = tid >> 4;

    // A tile loads: 128 rows x 8 k = 1024 floats; thread -> one float4 along k
    const int arow = tid >> 1;            // 0..127
    const int akk  = (tid & 1) << 2;      // 0 or 4
    // B tile loads: 8 k x 128 n; thread -> one float4 along n
    const int bkk  = tid >> 5;            // 0..7
    const int bcol = (tid & 31) << 2;     // 0..124

    const float* Aptr = A + (size_t)(bm + arow) * EDIM + akk;
    const float* Wptr = W + (size_t)bkk * EDIM + bn + bcol;

    float acc[8][8];
    #pragma unroll
    for (int i = 0; i < 8; ++i)
        #pragma unroll
        for (int j = 0; j < 8; ++j) acc[i][j] = 0.f;

    for (int k0 = 0; k0 < EDIM; k0 += 8) {
        float4 av = *(const float4*)(Aptr + k0);
        float4 bv = *(const float4*)(Wptr + (size_t)k0 * EDIM);
        __syncthreads();                       // protect previous iter's reads
        As[akk+0][arow] = av.x;
        As[akk+1][arow] = av.y;
        As[akk+2][arow] = av.z;
        As[akk+3][arow] = av.w;
        *(float4*)&Bs[bkk][bcol] = bv;
        __syncthreads();
        #pragma unroll
        for (int k = 0; k < 8; ++k) {
            float a[8], b[8];
            #pragma unroll
            for (int i = 0; i < 8; ++i) a[i] = As[k][ty*8 + i];
            #pragma unroll
            for (int j = 0; j < 8; ++j) b[j] = Bs[k][tx*8 + j];
            #pragma unroll
            for (int i = 0; i < 8; ++i)
                #pragma unroll
                for (int j = 0; j < 8; ++j) acc[i][j] = fmaf(a[i], b[j], acc[i][j]);
        }
    }

    float4 b0 = *(const float4*)(bias + bn + tx*8);
    float4 b1 = *(const float4*)(bias + bn + tx*8 + 4);
    #pragma unroll
    for (int i = 0; i < 8; ++i) {
        size_t row = (size_t)bm + ty*8 + i;
        float4 o0, o1;
        o0.x = (acc[i][0] + b0.x) * scale;
        o0.y = (acc[i][1] + b0.y) * scale;
        o0.z = (acc[i][2] + b0.z) * scale;
        o0.w = (acc[i][3] + b0.w) * scale;
        o1.x = (acc[i][4] + b1.x) * scale;
        o1.y = (acc[i][5] + b1.y) * scale;
        o1.z = (acc[i][6] + b1.z) * scale;
        o1.w = (acc[i][7] + b1.w) * scale;
        *(float4*)(out + row*EDIM + bn + tx*8)     = o0;
        *(float4*)(out + row*EDIM + bn + tx*8 + 4) = o1;
    }
}

// ============================================================================
// attn[h][i][j] = sum_{r,d} Q[r,i,h,d] * K[r,j,h,d]
// Q/K layout: [(r*C + c)*E + h*64 + d]. 64x64 output tile per block,
// k-loop over r (128 steps of d=64). 256 threads, 4x4 microtile.
// ============================================================================
__global__ __launch_bounds__(256)
void attn_logits(const float* __restrict__ Q, const float* __restrict__ K,
                 float* __restrict__ attn) {
    __shared__ float Qs[64][65];  // [d][i], pad 65 -> 2-way-max bank pattern
    __shared__ float Ks[64][65];  // [d][j]
    const int h  = blockIdx.x;
    const int i0 = blockIdx.y << 6;
    const int j0 = blockIdx.z << 6;
    const int tid = threadIdx.x;
    const int tx = tid & 15, ty = tid >> 4;
    const int lrow = tid >> 2;           // 0..63 (c within tile)
    const int lcol = (tid & 3) << 4;     // 0,16,32,48 (d chunk)

    float acc[4][4];
    #pragma unroll
    for (int i = 0; i < 4; ++i)
        #pragma unroll
        for (int j = 0; j < 4; ++j) acc[i][j] = 0.f;

    for (int r = 0; r < RDIM; ++r) {
        const float* qb = Q + ((size_t)(r*CDIM + i0 + lrow))*EDIM + h*DDIM + lcol;
        const float* kb = K + ((size_t)(r*CDIM + j0 + lrow))*EDIM + h*DDIM + lcol;
        float4 qv[4], kv[4];
        #pragma unroll
        for (int u = 0; u < 4; ++u) {
            qv[u] = *(const float4*)(qb + u*4);
            kv[u] = *(const float4*)(kb + u*4);
        }
        __syncthreads();
        #pragma unroll
        for (int u = 0; u < 4; ++u) {
            int d = lcol + u*4;
            Qs[d+0][lrow] = qv[u].x; Qs[d+1][lrow] = qv[u].y;
            Qs[d+2][lrow] = qv[u].z; Qs[d+3][lrow] = qv[u].w;
            Ks[d+0][lrow] = kv[u].x; Ks[d+1][lrow] = kv[u].y;
            Ks[d+2][lrow] = kv[u].z; Ks[d+3][lrow] = kv[u].w;
        }
        __syncthreads();
        #pragma unroll
        for (int d = 0; d < 64; ++d) {
            float a[4], b[4];
            #pragma unroll
            for (int i = 0; i < 4; ++i) a[i] = Qs[d][ty*4 + i];
            #pragma unroll
            for (int j = 0; j < 4; ++j) b[j] = Ks[d][tx*4 + j];
            #pragma unroll
            for (int i = 0; i < 4; ++i)
                #pragma unroll
                for (int j = 0; j < 4; ++j) acc[i][j] = fmaf(a[i], b[j], acc[i][j]);
        }
    }
    #pragma unroll
    for (int i = 0; i < 4; ++i) {
        size_t row = (size_t)h*CDIM + i0 + ty*4 + i;
        float4 o = {acc[i][0], acc[i][1], acc[i][2], acc[i][3]};
        *(float4*)(attn + row*CDIM + j0 + tx*4) = o;
    }
}

// ============================================================================
// In-place row softmax over last dim (512) for H*C = 6144 rows.
// ============================================================================
__global__ __launch_bounds__(256)
void softmax_rows(float* __restrict__ attn) {
    const int row = blockIdx.x;
    float* p = attn + (size_t)row * CDIM;
    const int tid = threadIdx.x;
    const int lane = tid & 63, wid = tid >> 6;
    __shared__ float red[8];

    float v0 = p[tid], v1 = p[tid + 256];
    float m = fmaxf(v0, v1);
    #pragma unroll
    for (int off = 32; off > 0; off >>= 1) m = fmaxf(m, __shfl_down(m, off));
    if (lane == 0) red[wid] = m;
    __syncthreads();
    if (tid == 0) red[4] = fmaxf(fmaxf(red[0], red[1]), fmaxf(red[2], red[3]));
    __syncthreads();
    const float M = red[4];

    float e0 = expf(v0 - M), e1 = expf(v1 - M);
    float s = e0 + e1;
    #pragma unroll
    for (int off = 32; off > 0; off >>= 1) s += __shfl_down(s, off);
    __syncthreads();                 // everyone done reading red[4]
    if (lane == 0) red[wid] = s;
    __syncthreads();
    if (tid == 0) red[5] = red[0] + red[1] + red[2] + red[3];
    __syncthreads();
    const float inv = 1.f / red[5];
    p[tid]       = e0 * inv;
    p[tid + 256] = e1 * inv;
}

// ============================================================================
// ctx[r,i,h,d] = sum_j P[h,i,j] * V[r,j,h,d]
// grid (r*H + h, i-tile). 64(i) x 64(d) tile, k-loop over j in chunks of 64.
// ============================================================================
__global__ __launch_bounds__(256)
void context_kernel(const float* __restrict__ P, const float* __restrict__ V,
                    float* __restrict__ ctx) {
    __shared__ float Ps[64][65];  // [j][i]
    __shared__ float Vs[64][68];  // [j][d] (pad 68 keeps float4 stores aligned)
    const int rh = blockIdx.x;
    const int r  = rh / HDIM;
    const int h  = rh % HDIM;
    const int i0 = blockIdx.y << 6;
    const int tid = threadIdx.x;
    const int tx = tid & 15, ty = tid >> 4;
    const int lr = tid >> 2;           // 0..63
    const int lc = (tid & 3) << 4;     // 0,16,32,48

    float acc[4][4];
    #pragma unroll
    for (int i = 0; i < 4; ++i)
        #pragma unroll
        for (int j = 0; j < 4; ++j) acc[i][j] = 0.f;

    for (int j0 = 0; j0 < CDIM; j0 += 64) {
        const float* pb = P + ((size_t)h*CDIM + i0 + lr)*CDIM + j0 + lc;
        const float* vb = V + ((size_t)(r*CDIM + j0 + lr))*EDIM + h*DDIM + lc;
        float4 pv[4], vv[4];
        #pragma unroll
        for (int u = 0; u < 4; ++u) {
            pv[u] = *(const float4*)(pb + u*4);
            vv[u] = *(const float4*)(vb + u*4);
        }
        __syncthreads();
        #pragma unroll
        for (int u = 0; u < 4; ++u) {
            int j = lc + u*4;
            Ps[j+0][lr] = pv[u].x; Ps[j+1][lr] = pv[u].y;
            Ps[j+2][lr] = pv[u].z; Ps[j+3][lr] = pv[u].w;
            *(float4*)&Vs[lr][lc + u*4] = vv[u];
        }
        __syncthreads();
        #pragma unroll
        for (int j = 0; j < 64; ++j) {
            float a[4], b[4];
            #pragma unroll
            for (int i = 0; i < 4; ++i) a[i] = Ps[j][ty*4 + i];
            #pragma unroll
            for (int d = 0; d < 4; ++d) b[d] = Vs[j][tx*4 + d];
            #pragma unroll
            for (int i = 0; i < 4; ++i)
                #pragma unroll
                for (int d = 0; d < 4; ++d) acc[i][d] = fmaf(a[i], b[d], acc[i][d]);
        }
    }
    #pragma unroll
    for (int i = 0; i < 4; ++i) {
        size_t row = (size_t)(r*CDIM + i0 + ty*4 + i);
        float4 o = {acc[i][0], acc[i][1], acc[i][2], acc[i][3]};
        *(float4*)(ctx + row*EDIM + h*DDIM + tx*4) = o;
    }
}

// ============================================================================
extern "C" void kernel_launch(void* const* d_in, const int* in_sizes, int n_in,
                              void* d_out, int out_size, void* d_ws, size_t ws_size,
                              hipStream_t stream) {
    const float* x  = (const float*)d_in[0];
    const float* Wq = (const float*)d_in[1];
    const float* bq = (const float*)d_in[2];
    const float* Wk = (const float*)d_in[3];
    const float* bk = (const float*)d_in[4];
    const float* Wv = (const float*)d_in[5];
    const float* bv = (const float*)d_in[6];
    const float* Wo = (const float*)d_in[7];
    const float* bo = (const float*)d_in[8];

    float* out   = (float*)d_out;
    float* attnp = out + OUT_ELEMS;           // attn_probs output region

    float* Qb = (float*)d_ws;                 // 201.3 MB each
    float* Kb = Qb + OUT_ELEMS;
    float* Vb = Kb + OUT_ELEMS;
    float* Cb = Qb;                           // context reuses Q buffer

    // scaling = head_dim^-0.5 / sqrt(num_rows) = 0.125 / sqrt(128)
    const float scaling = 0.011048543456039806f;

    dim3 gemm_grid(MDIM/128, EDIM/128);       // (512, 6)
    sgemm_bias<<<gemm_grid, 256, 0, stream>>>(x, Wq, bq, Qb, scaling);
    sgemm_bias<<<gemm_grid, 256, 0, stream>>>(x, Wk, bk, Kb, 1.f);
    sgemm_bias<<<gemm_grid, 256, 0, stream>>>(x, Wv, bv, Vb, 1.f);

    attn_logits<<<dim3(HDIM, CDIM/64, CDIM/64), 256, 0, stream>>>(Qb, Kb, attnp);
    softmax_rows<<<HDIM*CDIM, 256, 0, stream>>>(attnp);
    context_kernel<<<dim3(RDIM*HDIM, CDIM/64), 256, 0, stream>>>(attnp, Vb, Cb);

    sgemm_bias<<<gemm_grid, 256, 0, stream>>>(Cb, Wo, bo, out, 1.f);
}

// Round 2
// 993.037 us; speedup vs baseline: 5.7751x; 5.7751x over previous
//
#include <hip/hip_runtime.h>
#include <math.h>

#define RDIM 128
#define CDIM 512
#define EDIM 768
#define HDIM 12
#define DDIM 64
#define MDIM (RDIM*CDIM)                  // 65536 tokens
#define OUT_ELEMS ((size_t)MDIM*EDIM)     // output part of d_out
#define HSTRIDE ((size_t)CDIM*RDIM*DDIM)  // 4194304 elems per head (512*8192)

typedef unsigned short ushort_t;
typedef __attribute__((ext_vector_type(8))) short bf16x8;
typedef __attribute__((ext_vector_type(8))) unsigned short u16x8;
typedef __attribute__((ext_vector_type(4))) float f32x4;

__device__ __forceinline__ ushort_t f2bf(float f) {
    unsigned u = __float_as_uint(f);
    unsigned r = u + 0x7fffu + ((u >> 16) & 1u);   // round-to-nearest-even
    return (ushort_t)(r >> 16);
}

__device__ __forceinline__ void gload16(const void* g, void* l) {
    __builtin_amdgcn_global_load_lds(
        (const __attribute__((address_space(1))) unsigned int*)g,
        (__attribute__((address_space(3))) unsigned int*)l, 16, 0, 0);
}

// ============================================================================
// cast x (fp32) -> bf16, 8 elems/thread
// ============================================================================
__global__ __launch_bounds__(256)
void cast_x(const float* __restrict__ x, ushort_t* __restrict__ xb) {
    size_t i = ((size_t)blockIdx.x * 256 + threadIdx.x) * 8;
    float4 a = *(const float4*)&x[i];
    float4 b = *(const float4*)&x[i + 4];
    u16x8 o;
    o[0]=f2bf(a.x); o[1]=f2bf(a.y); o[2]=f2bf(a.z); o[3]=f2bf(a.w);
    o[4]=f2bf(b.x); o[5]=f2bf(b.y); o[6]=f2bf(b.z); o[7]=f2bf(b.w);
    *(u16x8*)&xb[i] = o;
}

// ============================================================================
// W[k][n] fp32 -> Wt[n][k] bf16   (768x768)
// ============================================================================
__global__ __launch_bounds__(256)
void transpose_cast_w(const float* __restrict__ W, ushort_t* __restrict__ Wt) {
    __shared__ ushort_t t[64][66];
    const int k0 = blockIdx.x * 64, n0 = blockIdx.y * 64;
    const int tx = threadIdx.x & 15, ty = threadIdx.x >> 4;
    #pragma unroll
    for (int rep = 0; rep < 4; ++rep) {
        int k = ty + rep * 16;
        float4 v = *(const float4*)&W[(size_t)(k0 + k) * EDIM + n0 + tx*4];
        t[k][tx*4+0] = f2bf(v.x); t[k][tx*4+1] = f2bf(v.y);
        t[k][tx*4+2] = f2bf(v.z); t[k][tx*4+3] = f2bf(v.w);
    }
    __syncthreads();
    #pragma unroll
    for (int rep = 0; rep < 4; ++rep) {
        int n = ty + rep * 16;
        ushort4 o = { t[tx*4+0][n], t[tx*4+1][n], t[tx*4+2][n], t[tx*4+3][n] };
        *(ushort4*)&Wt[(size_t)(n0 + n) * EDIM + k0 + tx*4] = o;
    }
}

// ============================================================================
// Vp[h][j][rd] -> Vt[h][rd][j]  (per head 512 x 8192, bf16)
// ============================================================================
__global__ __launch_bounds__(256)
void transpose_v(const ushort_t* __restrict__ Vp, ushort_t* __restrict__ Vt) {
    __shared__ ushort_t t[64][66];
    const size_t hb = (size_t)blockIdx.z * HSTRIDE;
    const int rd0 = blockIdx.x * 64, j0 = blockIdx.y * 64;
    const int tx = threadIdx.x & 15, ty = threadIdx.x >> 4;
    #pragma unroll
    for (int rep = 0; rep < 4; ++rep) {
        int j = ty + rep * 16;
        ushort4 v = *(const ushort4*)&Vp[hb + (size_t)(j0 + j) * 8192 + rd0 + tx*4];
        t[j][tx*4+0] = v.x; t[j][tx*4+1] = v.y; t[j][tx*4+2] = v.z; t[j][tx*4+3] = v.w;
    }
    __syncthreads();
    #pragma unroll
    for (int rep = 0; rep < 4; ++rep) {
        int rd = ty + rep * 16;
        ushort4 o = { t[tx*4+0][rd], t[tx*4+1][rd], t[tx*4+2][rd], t[tx*4+3][rd] };
        *(ushort4*)&Vt[hb + (size_t)(rd0 + rd) * CDIM + j0 + tx*4] = o;
    }
}

// ============================================================================
// BT-GEMM: C[m][n] = sum_k A[m][k]*B[n][k]  (A,B bf16, fp32 MFMA accumulate)
// 128x128 tile, BK=64, 4 waves (2x2), 64x64 per wave, 16x16x32 MFMA.
// MODE 0: per-head bf16 out (projections Q/K/V): (acc+bias[n])*scale at
//         [ (n>>6)*HSTRIDE + (m&511)*8192 + (m>>9)*64 + (n&63) ]
// MODE 1: token-major fp32 out + bias (final projection): out[m*N + n]
// MODE 2: attn logits fp32: out[h*262144 + m*512 + n]      (grid.z = head)
// MODE 3: context bf16 token-major: [((n>>6)*512 + m)*768 + h*64 + (n&63)]
// ============================================================================
template<int M, int N, int K, int MODE>
__global__ __launch_bounds__(256)
void gemm_bt(const ushort_t* __restrict__ A, const ushort_t* __restrict__ B,
             const float* __restrict__ bias, float scale,
             float* __restrict__ outF, ushort_t* __restrict__ outB,
             size_t sAh, size_t sBh) {
    __shared__ ushort_t As[128 * 64];
    __shared__ ushort_t Bs[128 * 64];
    const int tid  = threadIdx.x;
    const int lane = tid & 63, wave = tid >> 6;
    const int wr = wave >> 1, wc = wave & 1;
    const int fr = lane & 15, fs = lane >> 4;
    const int h = (MODE >= 2) ? blockIdx.z : 0;

    const ushort_t* Ab = A + (MODE >= 2 ? (size_t)h * sAh : 0)
                           + (size_t)(blockIdx.x * 128) * K;
    const ushort_t* Bb = B + (MODE >= 2 ? (size_t)h * sBh : 0)
                           + (size_t)(blockIdx.y * 128) * K;

    // staging map: chunk ci = it*256+tid covers 16B; row=ci>>3, seg=ci&7
    size_t goff[4];
    int loff[4];
    #pragma unroll
    for (int it = 0; it < 4; ++it) {
        int ci = it * 256 + tid;
        goff[it] = (size_t)(ci >> 3) * K + (ci & 7) * 8;
        loff[it] = ci * 16;
    }

    f32x4 acc[4][4];
    #pragma unroll
    for (int i = 0; i < 4; ++i)
        #pragma unroll
        for (int j = 0; j < 4; ++j) acc[i][j] = (f32x4){0.f, 0.f, 0.f, 0.f};

    for (int k0 = 0; k0 < K; k0 += 64) {
        #pragma unroll
        for (int it = 0; it < 4; ++it) {
            gload16(Ab + goff[it] + k0, (char*)As + loff[it]);
            gload16(Bb + goff[it] + k0, (char*)Bs + loff[it]);
        }
        __syncthreads();
        #pragma unroll
        for (int kk = 0; kk < 2; ++kk) {
            bf16x8 af[4], bf[4];
            #pragma unroll
            for (int mi = 0; mi < 4; ++mi)
                af[mi] = *(const bf16x8*)&As[(wr*64 + mi*16 + fr)*64 + kk*32 + fs*8];
            #pragma unroll
            for (int ni = 0; ni < 4; ++ni)
                bf[ni] = *(const bf16x8*)&Bs[(wc*64 + ni*16 + fr)*64 + kk*32 + fs*8];
            #pragma unroll
            for (int mi = 0; mi < 4; ++mi)
                #pragma unroll
                for (int ni = 0; ni < 4; ++ni)
                    acc[mi][ni] = __builtin_amdgcn_mfma_f32_16x16x32_bf16(
                        af[mi], bf[ni], acc[mi][ni], 0, 0, 0);
        }
        __syncthreads();
    }

    // epilogue: acc[mi][ni][j] -> row m, col n
    #pragma unroll
    for (int mi = 0; mi < 4; ++mi) {
        #pragma unroll
        for (int ni = 0; ni < 4; ++ni) {
            const int n = blockIdx.y*128 + wc*64 + ni*16 + fr;
            float bv = 0.f;
            if (MODE == 0 || MODE == 1) bv = bias[n];
            #pragma unroll
            for (int j = 0; j < 4; ++j) {
                const int m = blockIdx.x*128 + wr*64 + mi*16 + fs*4 + j;
                float v = acc[mi][ni][j];
                if (MODE == 0) {
                    v = (v + bv) * scale;
                    size_t addr = (size_t)(n >> 6) * HSTRIDE
                                + (size_t)(m & 511) * 8192 + (m >> 9) * 64 + (n & 63);
                    outB[addr] = f2bf(v);
                } else if (MODE == 1) {
                    outF[(size_t)m * N + n] = v + bv;
                } else if (MODE == 2) {
                    outF[(size_t)h * CDIM * CDIM + (size_t)m * CDIM + n] = v;
                } else { // MODE 3
                    size_t addr = ((size_t)(n >> 6) * CDIM + m) * EDIM
                                + h * DDIM + (n & 63);
                    outB[addr] = f2bf(v);
                }
            }
        }
    }
}

// ============================================================================
// row softmax over last dim (512) for H*C rows; fp32 in-place + bf16 copy
// ============================================================================
__global__ __launch_bounds__(256)
void softmax_rows(float* __restrict__ attn, ushort_t* __restrict__ Pb) {
    const int row = blockIdx.x;
    float* p = attn + (size_t)row * CDIM;
    ushort_t* pb = Pb + (size_t)row * CDIM;
    const int tid = threadIdx.x;
    const int lane = tid & 63, wid = tid >> 6;
    __shared__ float red[8];

    float v0 = p[tid], v1 = p[tid + 256];
    float m = fmaxf(v0, v1);
    #pragma unroll
    for (int off = 32; off > 0; off >>= 1) m = fmaxf(m, __shfl_down(m, off));
    if (lane == 0) red[wid] = m;
    __syncthreads();
    if (tid == 0) red[4] = fmaxf(fmaxf(red[0], red[1]), fmaxf(red[2], red[3]));
    __syncthreads();
    const float M = red[4];

    float e0 = expf(v0 - M), e1 = expf(v1 - M);
    float s = e0 + e1;
    #pragma unroll
    for (int off = 32; off > 0; off >>= 1) s += __shfl_down(s, off);
    __syncthreads();
    if (lane == 0) red[wid] = s;
    __syncthreads();
    if (tid == 0) red[5] = red[0] + red[1] + red[2] + red[3];
    __syncthreads();
    const float inv = 1.f / red[5];
    float o0 = e0 * inv, o1 = e1 * inv;
    p[tid] = o0;          p[tid + 256] = o1;
    pb[tid] = f2bf(o0);   pb[tid + 256] = f2bf(o1);
}

// ============================================================================
extern "C" void kernel_launch(void* const* d_in, const int* in_sizes, int n_in,
                              void* d_out, int out_size, void* d_ws, size_t ws_size,
                              hipStream_t stream) {
    const float* x  = (const float*)d_in[0];
    const float* Wq = (const float*)d_in[1];
    const float* bq = (const float*)d_in[2];
    const float* Wk = (const float*)d_in[3];
    const float* bk = (const float*)d_in[4];
    const float* Wv = (const float*)d_in[5];
    const float* bv = (const float*)d_in[6];
    const float* Wo = (const float*)d_in[7];
    const float* bo = (const float*)d_in[8];

    float* out   = (float*)d_out;
    float* attnp = out + OUT_ELEMS;            // attn_probs fp32 output region

    // workspace layout (ushort units)
    ushort_t* ws  = (ushort_t*)d_ws;
    ushort_t* xb  = ws;                                   // 50331648
    ushort_t* Wtq = xb  + OUT_ELEMS;                      // 589824 each
    ushort_t* Wtk = Wtq + 589824;
    ushort_t* Wtv = Wtk + 589824;
    ushort_t* Wto = Wtv + 589824;
    ushort_t* Qp  = Wto + 589824;                         // [12][512][8192]
    ushort_t* Kp  = Qp  + OUT_ELEMS;
    ushort_t* Vp  = Kp  + OUT_ELEMS;                      // [12][512][8192]
    ushort_t* Vt  = Vp  + OUT_ELEMS;                      // [12][8192][512]
    ushort_t* Pb  = Vt  + OUT_ELEMS;                      // [12][512][512]
    ushort_t* ctxb = Vp;                                  // reuse Vp after transpose

    const float scaling = 0.011048543456039806f;  // 64^-0.5 / sqrt(128)

    // 1. casts / weight transposes
    cast_x<<<MDIM*EDIM/(256*8), 256, 0, stream>>>(x, xb);
    dim3 wt(EDIM/64, EDIM/64);
    transpose_cast_w<<<wt, 256, 0, stream>>>(Wq, Wtq);
    transpose_cast_w<<<wt, 256, 0, stream>>>(Wk, Wtk);
    transpose_cast_w<<<wt, 256, 0, stream>>>(Wv, Wtv);
    transpose_cast_w<<<wt, 256, 0, stream>>>(Wo, Wto);

    // 2. projections -> per-head layouts (bf16)
    dim3 pg(MDIM/128, EDIM/128);
    gemm_bt<MDIM, EDIM, EDIM, 0><<<pg, 256, 0, stream>>>(xb, Wtq, bq, scaling, nullptr, Qp, 0, 0);
    gemm_bt<MDIM, EDIM, EDIM, 0><<<pg, 256, 0, stream>>>(xb, Wtk, bk, 1.f,     nullptr, Kp, 0, 0);
    gemm_bt<MDIM, EDIM, EDIM, 0><<<pg, 256, 0, stream>>>(xb, Wtv, bv, 1.f,     nullptr, Vp, 0, 0);

    // 3. V transpose: [h][j][rd] -> [h][rd][j]
    transpose_v<<<dim3(8192/64, CDIM/64, HDIM), 256, 0, stream>>>(Vp, Vt);

    // 4. attn logits: per head 512x512xK8192 -> fp32 attnp
    gemm_bt<CDIM, CDIM, 8192, 2><<<dim3(4, 4, HDIM), 256, 0, stream>>>(
        Qp, Kp, nullptr, 1.f, attnp, nullptr, HSTRIDE, HSTRIDE);

    // 5. softmax (fp32 out + bf16 copy)
    softmax_rows<<<HDIM*CDIM, 256, 0, stream>>>(attnp, Pb);

    // 6. context: per head 512x8192xK512 -> bf16 token-major
    gemm_bt<CDIM, 8192, CDIM, 3><<<dim3(4, 64, HDIM), 256, 0, stream>>>(
        Pb, Vt, nullptr, 1.f, nullptr, ctxb, (size_t)CDIM*CDIM, HSTRIDE);

    // 7. output projection (fp32 + bias)
    gemm_bt<MDIM, EDIM, EDIM, 1><<<pg, 256, 0, stream>>>(ctxb, Wto, bo, 1.f, out, nullptr, 0, 0);
}

// Round 3
// 850.117 us; speedup vs baseline: 6.7460x; 1.1681x over previous
//
#include <hip/hip_runtime.h>
#include <math.h>

#define RDIM 128
#define CDIM 512
#define EDIM 768
#define HDIM 12
#define DDIM 64
#define MDIM (RDIM*CDIM)                  // 65536 tokens
#define OUT_ELEMS ((size_t)MDIM*EDIM)     // 50331648
#define HSTRIDE ((size_t)CDIM*RDIM*DDIM)  // 4194304 elems per head (512*8192)
#define WELEMS (EDIM*EDIM)                // 589824

typedef unsigned short ushort_t;
typedef __attribute__((ext_vector_type(8))) short bf16x8;
typedef __attribute__((ext_vector_type(8))) unsigned short u16x8;
typedef __attribute__((ext_vector_type(4))) float f32x4;

__device__ __forceinline__ ushort_t f2bf(float f) {
    unsigned u = __float_as_uint(f);
    unsigned r = u + 0x7fffu + ((u >> 16) & 1u);   // round-to-nearest-even
    return (ushort_t)(r >> 16);
}

__device__ __forceinline__ void gload16(const void* g, void* l) {
    __builtin_amdgcn_global_load_lds(
        (const __attribute__((address_space(1))) unsigned int*)g,
        (__attribute__((address_space(3))) unsigned int*)l, 16, 0, 0);
}

// ============================================================================
// cast x (fp32) -> bf16, 8 elems/thread
// ============================================================================
__global__ __launch_bounds__(256)
void cast_x(const float* __restrict__ x, ushort_t* __restrict__ xb) {
    size_t i = ((size_t)blockIdx.x * 256 + threadIdx.x) * 8;
    float4 a = *(const float4*)&x[i];
    float4 b = *(const float4*)&x[i + 4];
    u16x8 o;
    o[0]=f2bf(a.x); o[1]=f2bf(a.y); o[2]=f2bf(a.z); o[3]=f2bf(a.w);
    o[4]=f2bf(b.x); o[5]=f2bf(b.y); o[6]=f2bf(b.z); o[7]=f2bf(b.w);
    *(u16x8*)&xb[i] = o;
}

// ============================================================================
// W[k][n] fp32 -> Wt[n][k] bf16   (768x768)
// ============================================================================
__global__ __launch_bounds__(256)
void transpose_cast_w(const float* __restrict__ W, ushort_t* __restrict__ Wt) {
    __shared__ ushort_t t[64][66];
    const int k0 = blockIdx.x * 64, n0 = blockIdx.y * 64;
    const int tx = threadIdx.x & 15, ty = threadIdx.x >> 4;
    #pragma unroll
    for (int rep = 0; rep < 4; ++rep) {
        int k = ty + rep * 16;
        float4 v = *(const float4*)&W[(size_t)(k0 + k) * EDIM + n0 + tx*4];
        t[k][tx*4+0] = f2bf(v.x); t[k][tx*4+1] = f2bf(v.y);
        t[k][tx*4+2] = f2bf(v.z); t[k][tx*4+3] = f2bf(v.w);
    }
    __syncthreads();
    #pragma unroll
    for (int rep = 0; rep < 4; ++rep) {
        int n = ty + rep * 16;
        ushort4 o = { t[tx*4+0][n], t[tx*4+1][n], t[tx*4+2][n], t[tx*4+3][n] };
        *(ushort4*)&Wt[(size_t)(n0 + n) * EDIM + k0 + tx*4] = o;
    }
}

// ============================================================================
// concat biases -> bqkv[2304] fp32
// ============================================================================
__global__ __launch_bounds__(256)
void concat_bias(const float* __restrict__ bq, const float* __restrict__ bk,
                 const float* __restrict__ bv, float* __restrict__ bqkv) {
    int i = blockIdx.x * 256 + threadIdx.x;
    if (i < 768)        bqkv[i] = bq[i];
    else if (i < 1536)  bqkv[i] = bk[i - 768];
    else if (i < 2304)  bqkv[i] = bv[i - 1536];
}

// ============================================================================
// BT-GEMM: C[m][n] = sum_k A[m][k]*B[n][k]  (bf16 in, fp32 MFMA accumulate)
// 128x128 tile, BK=64, 4 waves (2x2), 16x16x32 MFMA. LDK = A/B row stride.
// MODE 1: token-major fp32 out + bias (final projection): out[m*N + n]
// MODE 2: split-K attn logits: z=h*4+s, A/B k-offset s*2048,
//         partials out[z*262144 + m*512 + n]
// MODE 3: context bf16 token-major: [((n>>6)*512 + m)*768 + h*64 + (n&63)]
// MODE 4: fused QKV: by/6 selects Q|K|V. Q,K -> per-head [h][c][r*64+d];
//         V -> LDS-transposed direct store to Vt [h][rd][j].
//         outB = Qp base; Kp = outB + OUT_ELEMS; Vt = outB + 2*OUT_ELEMS.
// ============================================================================
template<int M, int N, int K, int LDK, int MODE>
__global__ __launch_bounds__(256)
void gemm_bt(const ushort_t* __restrict__ A, const ushort_t* __restrict__ B,
             const float* __restrict__ bias, float scale,
             float* __restrict__ outF, ushort_t* __restrict__ outB,
             size_t sAh, size_t sBh) {
    constexpr int SMEM_BYTES = (MODE == 4) ? 33280 : 32768;
    __shared__ __align__(16) char smem[SMEM_BYTES];
    ushort_t* As = (ushort_t*)smem;
    ushort_t* Bs = (ushort_t*)(smem + 16384);

    const int tid  = threadIdx.x;
    const int lane = tid & 63, wave = tid >> 6;
    const int wr = wave >> 1, wc = wave & 1;
    const int fr = lane & 15, fs = lane >> 4;

    int h = 0, ksub = 0;
    if (MODE == 2) { h = blockIdx.z >> 2; ksub = blockIdx.z & 3; }
    if (MODE == 3) { h = blockIdx.z; }

    const int bm = blockIdx.x * 128;
    const ushort_t* Ab = A + (MODE == 2 || MODE == 3 ? (size_t)h * sAh : 0)
                           + (MODE == 2 ? (size_t)ksub * 2048 : 0)
                           + (size_t)bm * LDK;
    const ushort_t* Bb = B + (MODE == 2 || MODE == 3 ? (size_t)h * sBh : 0)
                           + (MODE == 2 ? (size_t)ksub * 2048 : 0)
                           + (size_t)(blockIdx.y * 128) * LDK;

    size_t goff[4];
    int loff[4];
    #pragma unroll
    for (int it = 0; it < 4; ++it) {
        int ci = it * 256 + tid;
        goff[it] = (size_t)(ci >> 3) * LDK + (ci & 7) * 8;
        loff[it] = ci * 16;
    }

    f32x4 acc[4][4];
    #pragma unroll
    for (int i = 0; i < 4; ++i)
        #pragma unroll
        for (int j = 0; j < 4; ++j) acc[i][j] = (f32x4){0.f, 0.f, 0.f, 0.f};

    for (int k0 = 0; k0 < K; k0 += 64) {
        #pragma unroll
        for (int it = 0; it < 4; ++it) {
            gload16(Ab + goff[it] + k0, (char*)smem + loff[it]);
            gload16(Bb + goff[it] + k0, (char*)smem + 16384 + loff[it]);
        }
        __syncthreads();
        #pragma unroll
        for (int kk = 0; kk < 2; ++kk) {
            bf16x8 af[4], bfr[4];
            #pragma unroll
            for (int mi = 0; mi < 4; ++mi)
                af[mi] = *(const bf16x8*)&As[(wr*64 + mi*16 + fr)*64 + kk*32 + fs*8];
            #pragma unroll
            for (int ni = 0; ni < 4; ++ni)
                bfr[ni] = *(const bf16x8*)&Bs[(wc*64 + ni*16 + fr)*64 + kk*32 + fs*8];
            #pragma unroll
            for (int mi = 0; mi < 4; ++mi)
                #pragma unroll
                for (int ni = 0; ni < 4; ++ni)
                    acc[mi][ni] = __builtin_amdgcn_mfma_f32_16x16x32_bf16(
                        af[mi], bfr[ni], acc[mi][ni], 0, 0, 0);
        }
        __syncthreads();
    }

    if (MODE == 4) {
        const int which = blockIdx.y / 6;          // 0=Q,1=K,2=V (block-uniform)
        const int nb = (blockIdx.y % 6) * 128;     // hcol base
        if (which < 2) {
            ushort_t* dst = outB + (size_t)which * OUT_ELEMS;
            const float sc = (which == 0) ? scale : 1.f;
            #pragma unroll
            for (int mi = 0; mi < 4; ++mi) {
                #pragma unroll
                for (int ni = 0; ni < 4; ++ni) {
                    const int hcol = nb + wc*64 + ni*16 + fr;
                    const float bv = bias[which*768 + hcol];
                    const int hh = hcol >> 6, d = hcol & 63;
                    #pragma unroll
                    for (int j = 0; j < 4; ++j) {
                        const int m = bm + wr*64 + mi*16 + fs*4 + j;
                        float v = (acc[mi][ni][j] + bv) * sc;
                        size_t addr = (size_t)hh * HSTRIDE
                                    + (size_t)(m & 511) * 8192 + (m >> 9) * 64 + d;
                        dst[addr] = f2bf(v);
                    }
                }
            }
        } else {
            // V: transpose through LDS, coalesced stores to Vt[h][rd][j]
            ushort_t* Ts = (ushort_t*)smem;        // [128][130]
            __syncthreads();
            #pragma unroll
            for (int mi = 0; mi < 4; ++mi) {
                #pragma unroll
                for (int ni = 0; ni < 4; ++ni) {
                    const int nl = wc*64 + ni*16 + fr;
                    const float bv = bias[1536 + nb + nl];
                    #pragma unroll
                    for (int j = 0; j < 4; ++j) {
                        const int ml = wr*64 + mi*16 + fs*4 + j;
                        Ts[nl*130 + ml] = f2bf(acc[mi][ni][j] + bv);
                    }
                }
            }
            __syncthreads();
            ushort_t* dst = outB + 2 * OUT_ELEMS;
            const int base_h = nb >> 6;
            const int rblk = bm >> 9, jb = bm & 511;
            #pragma unroll
            for (int it = 0; it < 8; ++it) {
                const int idx = it * 256 + tid;
                const int row = idx >> 4, col8 = (idx & 15) * 8;
                const int hh = base_h + (row >> 6), d = row & 63;
                uint4 wv;
                wv.x = *(const uint*)&Ts[row*130 + col8];
                wv.y = *(const uint*)&Ts[row*130 + col8 + 2];
                wv.z = *(const uint*)&Ts[row*130 + col8 + 4];
                wv.w = *(const uint*)&Ts[row*130 + col8 + 6];
                size_t addr = (size_t)hh * HSTRIDE
                            + (size_t)(rblk*64 + d) * CDIM + jb + col8;
                *(uint4*)&dst[addr] = wv;
            }
        }
        return;
    }

    #pragma unroll
    for (int mi = 0; mi < 4; ++mi) {
        #pragma unroll
        for (int ni = 0; ni < 4; ++ni) {
            const int n = blockIdx.y*128 + wc*64 + ni*16 + fr;
            float bv = (MODE == 1) ? bias[n] : 0.f;
            #pragma unroll
            for (int j = 0; j < 4; ++j) {
                const int m = bm + wr*64 + mi*16 + fs*4 + j;
                float v = acc[mi][ni][j];
                if (MODE == 1) {
                    outF[(size_t)m * N + n] = v + bv;
                } else if (MODE == 2) {
                    outF[(size_t)blockIdx.z * (CDIM*CDIM) + (size_t)m * CDIM + n] = v;
                } else { // MODE 3
                    size_t addr = ((size_t)(n >> 6) * CDIM + m) * EDIM
                                + h * DDIM + (n & 63);
                    outB[addr] = f2bf(v);
                }
            }
        }
    }
}

// ============================================================================
// softmax over 512 cols for H*C rows; sums 4 split-K partials first.
// fp32 probs -> attn (d_out), bf16 copy -> Pb.
// ============================================================================
__global__ __launch_bounds__(256)
void softmax_reduce(const float* __restrict__ part, float* __restrict__ attn,
                    ushort_t* __restrict__ Pb) {
    const int row = blockIdx.x;              // h*512 + c
    const int h = row >> 9, c = row & 511;
    const int tid = threadIdx.x;
    const int lane = tid & 63, wid = tid >> 6;
    __shared__ float red[8];

    float v0 = 0.f, v1 = 0.f;
    #pragma unroll
    for (int s = 0; s < 4; ++s) {
        const float* p = part + ((size_t)(h*4 + s) * (CDIM*CDIM)) + (size_t)c * CDIM;
        v0 += p[tid];
        v1 += p[tid + 256];
    }
    float m = fmaxf(v0, v1);
    #pragma unroll
    for (int off = 32; off > 0; off >>= 1) m = fmaxf(m, __shfl_down(m, off));
    if (lane == 0) red[wid] = m;
    __syncthreads();
    if (tid == 0) red[4] = fmaxf(fmaxf(red[0], red[1]), fmaxf(red[2], red[3]));
    __syncthreads();
    const float M = red[4];

    float e0 = expf(v0 - M), e1 = expf(v1 - M);
    float s = e0 + e1;
    #pragma unroll
    for (int off = 32; off > 0; off >>= 1) s += __shfl_down(s, off);
    __syncthreads();
    if (lane == 0) red[wid] = s;
    __syncthreads();
    if (tid == 0) red[5] = red[0] + red[1] + red[2] + red[3];
    __syncthreads();
    const float inv = 1.f / red[5];
    float o0 = e0 * inv, o1 = e1 * inv;
    float* pout = attn + (size_t)row * CDIM;
    ushort_t* pb = Pb + (size_t)row * CDIM;
    pout[tid] = o0;        pout[tid + 256] = o1;
    pb[tid]   = f2bf(o0);  pb[tid + 256]   = f2bf(o1);
}

// ============================================================================
extern "C" void kernel_launch(void* const* d_in, const int* in_sizes, int n_in,
                              void* d_out, int out_size, void* d_ws, size_t ws_size,
                              hipStream_t stream) {
    const float* x  = (const float*)d_in[0];
    const float* Wq = (const float*)d_in[1];
    const float* bq = (const float*)d_in[2];
    const float* Wk = (const float*)d_in[3];
    const float* bk = (const float*)d_in[4];
    const float* Wv = (const float*)d_in[5];
    const float* bv = (const float*)d_in[6];
    const float* Wo = (const float*)d_in[7];
    const float* bo = (const float*)d_in[8];

    float* out   = (float*)d_out;
    float* attnp = out + OUT_ELEMS;            // attn_probs fp32 output region

    // workspace layout (ushort units)
    ushort_t* ws   = (ushort_t*)d_ws;
    ushort_t* xb   = ws;                                   // 100 MB; reused as ctxb
    ushort_t* Wqkv = xb + OUT_ELEMS;                       // [2304][768]
    ushort_t* Wto  = Wqkv + 3*WELEMS;
    float*    bqkv = (float*)(Wto + WELEMS);               // 2304 fp32
    ushort_t* Qp   = Wto + WELEMS + 4608;                  // [12][512][8192]
    ushort_t* Kp   = Qp + OUT_ELEMS;                       // contiguous after Qp
    ushort_t* Vt   = Kp + OUT_ELEMS;                       // [12][8192][512]
    ushort_t* Pb   = Vt + OUT_ELEMS;                       // [12][512][512]
    float*    part = (float*)(Pb + (size_t)HDIM*CDIM*CDIM); // 48 planes fp32
    ushort_t* ctxb = xb;                                   // reuse after QKV GEMM

    const float scaling = 0.011048543456039806f;  // 64^-0.5 / sqrt(128)

    // 1. casts / weight transposes / bias concat
    cast_x<<<MDIM*EDIM/(256*8), 256, 0, stream>>>(x, xb);
    dim3 wt(EDIM/64, EDIM/64);
    transpose_cast_w<<<wt, 256, 0, stream>>>(Wq, Wqkv);
    transpose_cast_w<<<wt, 256, 0, stream>>>(Wk, Wqkv + WELEMS);
    transpose_cast_w<<<wt, 256, 0, stream>>>(Wv, Wqkv + 2*WELEMS);
    transpose_cast_w<<<wt, 256, 0, stream>>>(Wo, Wto);
    concat_bias<<<9, 256, 0, stream>>>(bq, bk, bv, bqkv);

    // 2. fused QKV projection (Q,K per-head; V direct-transposed)
    gemm_bt<MDIM, 2304, EDIM, EDIM, 4><<<dim3(512, 18), 256, 0, stream>>>(
        xb, Wqkv, bqkv, scaling, nullptr, Qp, 0, 0);

    // 3. attn logits, split-K=4: per head 512x512, K-chunks of 2048
    gemm_bt<CDIM, CDIM, 2048, 8192, 2><<<dim3(4, 4, 48), 256, 0, stream>>>(
        Qp, Kp, nullptr, 1.f, part, nullptr, HSTRIDE, HSTRIDE);

    // 4. softmax (+4-way partial reduce), fp32 out + bf16 copy
    softmax_reduce<<<HDIM*CDIM, 256, 0, stream>>>(part, attnp, Pb);

    // 5. context: per head 512x8192xK512 -> bf16 token-major
    gemm_bt<CDIM, 8192, CDIM, CDIM, 3><<<dim3(4, 64, 12), 256, 0, stream>>>(
        Pb, Vt, nullptr, 1.f, nullptr, ctxb, (size_t)CDIM*CDIM, HSTRIDE);

    // 6. output projection (fp32 + bias)
    gemm_bt<MDIM, EDIM, EDIM, EDIM, 1><<<dim3(512, 6), 256, 0, stream>>>(
        ctxb, Wto, bo, 1.f, out, nullptr, 0, 0);
}